// Round 3
// baseline (6677.422 us; speedup 1.0000x reference)
//
#include <hip/hip_runtime.h>

#define TT 2048
#define BB 256
#define HID 64

typedef float f32x4 __attribute__((ext_vector_type(4)));

__device__ __forceinline__ float frcp(float x) { return __builtin_amdgcn_rcpf(x); }
__device__ __forceinline__ float fsig(float x) { return frcp(1.f + __expf(-x)); }
// tanh(x) = 1 - 2/(1+e^{2x}) : stable at +/-inf (no inf-inf)
__device__ __forceinline__ float ftanh(float x) { return 1.f - 2.f * frcp(1.f + __expf(2.f * x)); }

// pre = in(R,K) @ W(256,K)^T + b_ih + b_hh  -> out(R,256)
// block: 256 threads, tile 64 rows x 256 cols, k-chunks of 16.  (unchanged, proven)
__global__ __launch_bounds__(256, 2) void gemm_pre_k(
    const float* __restrict__ in, const float* __restrict__ W,
    const float* __restrict__ b_ih, const float* __restrict__ b_hh,
    float* __restrict__ out, int K)
{
    __shared__ __align__(16) float in_s[64][20];   // +4 pad keeps float4 align, breaks conflicts
    __shared__ __align__(16) float w_s[16][256];   // transposed W chunk: w_s[k][g]

    const int tid = threadIdx.x;
    const int tx = tid & 15, ty = tid >> 4;
    const long long row0 = (long long)blockIdx.x * 64;

    float4 bias[4];
    {
        const float4* bi4 = (const float4*)b_ih;
        const float4* bh4 = (const float4*)b_hh;
#pragma unroll
        for (int jj = 0; jj < 4; ++jj) {
            float4 a = bi4[tx * 4 + jj], b = bh4[tx * 4 + jj];
            bias[jj] = make_float4(a.x + b.x, a.y + b.y, a.z + b.z, a.w + b.w);
        }
    }

    float4 acc[4][4];
#pragma unroll
    for (int i = 0; i < 4; ++i)
#pragma unroll
        for (int j = 0; j < 4; ++j) acc[i][j] = make_float4(0.f, 0.f, 0.f, 0.f);

    const int rs = tid >> 2;   // 0..63 staging row
    const int kq = tid & 3;    // 0..3 staging k-quarter

    for (int kc = 0; kc < K; kc += 16) {
        __syncthreads();
        float4 iv = *(const float4*)(in + (row0 + rs) * K + kc + kq * 4);
        *(float4*)(&in_s[rs][kq * 4]) = iv;
        const float* wr = W + (long long)tid * K + kc;
        float4 w0 = ((const float4*)wr)[0];
        float4 w1 = ((const float4*)wr)[1];
        float4 w2 = ((const float4*)wr)[2];
        float4 w3 = ((const float4*)wr)[3];
        w_s[0][tid] = w0.x;  w_s[1][tid] = w0.y;  w_s[2][tid] = w0.z;  w_s[3][tid] = w0.w;
        w_s[4][tid] = w1.x;  w_s[5][tid] = w1.y;  w_s[6][tid] = w1.z;  w_s[7][tid] = w1.w;
        w_s[8][tid] = w2.x;  w_s[9][tid] = w2.y;  w_s[10][tid] = w2.z; w_s[11][tid] = w2.w;
        w_s[12][tid] = w3.x; w_s[13][tid] = w3.y; w_s[14][tid] = w3.z; w_s[15][tid] = w3.w;
        __syncthreads();

#pragma unroll
        for (int k2 = 0; k2 < 4; ++k2) {
            float4 a[4];
#pragma unroll
            for (int i = 0; i < 4; ++i) a[i] = *(const float4*)(&in_s[ty * 4 + i][k2 * 4]);
#pragma unroll
            for (int kk = 0; kk < 4; ++kk) {
                const int k = k2 * 4 + kk;
                float4 wv[4];
#pragma unroll
                for (int jj = 0; jj < 4; ++jj) wv[jj] = *(const float4*)(&w_s[k][tx * 16 + jj * 4]);
#pragma unroll
                for (int i = 0; i < 4; ++i) {
                    const float av = ((const float*)&a[i])[kk];
#pragma unroll
                    for (int jj = 0; jj < 4; ++jj) {
                        acc[i][jj].x += av * wv[jj].x;
                        acc[i][jj].y += av * wv[jj].y;
                        acc[i][jj].z += av * wv[jj].z;
                        acc[i][jj].w += av * wv[jj].w;
                    }
                }
            }
        }
    }

#pragma unroll
    for (int i = 0; i < 4; ++i) {
        float4* op = (float4*)(out + (row0 + ty * 4 + i) * 256 + tx * 16);
#pragma unroll
        for (int jj = 0; jj < 4; ++jj) {
            float4 v = acc[i][jj];
            v.x += bias[jj].x; v.y += bias[jj].y; v.z += bias[jj].z; v.w += bias[jj].w;
            op[jj] = v;
        }
    }
}

// Recurrent kernel — ONE WAVE per batch element, gates lane-local.
//  - 64 threads/block, block b = batch element b. Lane j owns h-index j and
//    computes all four of its gates (W_hh rows j, j+64, j+128, j+192 live in
//    256 VGPRs; legal at 1 wave/SIMD via __launch_bounds__(64,1)).
//  - NO barriers, NO cross-wave exchange. Only LDS use: 64-float h broadcast,
//    wave-uniform ds_read_b128 (conflict-free), write->read ordered within
//    the wave by compiler-inserted lgkmcnt.
//  - dot products as f32x4 ops -> v_pk_fma_f32; 4 gate accumulators share
//    each h broadcast read.
//  - pre[] fetched as 4 coalesced dword loads/step, 3 steps deep (12 loads
//    in flight > HBM latency); h store fire-and-forget.
__global__ __launch_bounds__(64, 1) void lstm_rec_k(
    const float* __restrict__ pre, const float* __restrict__ w_hh,
    float* __restrict__ h_out)
{
    __shared__ __align__(16) float h_s[HID];

    const int j = threadIdx.x;   // 0..63 = h index
    const int b = blockIdx.x;

    // W_hh rows for lane j's four gates: 4 x 64 floats = 256 VGPRs
    f32x4 wq[4][16];
#pragma unroll
    for (int q = 0; q < 4; ++q) {
        const f32x4* wr = (const f32x4*)(w_hh + (q * HID + j) * HID);
#pragma unroll
        for (int k = 0; k < 16; ++k) wq[q][k] = wr[k];
    }

    h_s[j] = 0.f;
    float c = 0.f;

    // 3-deep prefetch of pre[b][t][q*64+j], q=0..3
    const float* pp = pre + (long long)b * TT * 256;
    float4 pA, pB, pC;
    pA.x = pp[j]; pA.y = pp[64 + j]; pA.z = pp[128 + j]; pA.w = pp[192 + j]; pp += 256;
    pB.x = pp[j]; pB.y = pp[64 + j]; pB.z = pp[128 + j]; pB.w = pp[192 + j]; pp += 256;
    pC.x = pp[j]; pC.y = pp[64 + j]; pC.z = pp[128 + j]; pC.w = pp[192 + j]; pp += 256;

    float* hop = h_out + (long long)b * TT * HID + j;

    for (int t = 0; t < TT; ++t) {
        // ---- 4 gate dots over the h broadcast (shared ds_read per k) ----
        f32x4 a0 = (f32x4)(0.f), a1 = (f32x4)(0.f), a2 = (f32x4)(0.f), a3 = (f32x4)(0.f);
        const f32x4* h4 = (const f32x4*)h_s;
#pragma unroll
        for (int k = 0; k < 16; ++k) {
            f32x4 hv = h4[k];            // wave-uniform broadcast read
            a0 += wq[0][k] * hv;
            a1 += wq[1][k] * hv;
            a2 += wq[2][k] * hv;
            a3 += wq[3][k] * hv;
        }
        float gi = pA.x + ((a0.x + a0.y) + (a0.z + a0.w));
        float gf = pA.y + ((a1.x + a1.y) + (a1.z + a1.w));
        float gg = pA.z + ((a2.x + a2.y) + (a2.z + a2.w));
        float go = pA.w + ((a3.x + a3.y) + (a3.z + a3.w));

        // rotate prefetch queue, issue t+3 (stays in flight)
        pA = pB; pB = pC;
        if (t + 3 < TT) {
            pC.x = pp[j]; pC.y = pp[64 + j]; pC.z = pp[128 + j]; pC.w = pp[192 + j];
        }
        pp += 256;

        // ---- activations + state update (all lane-local) ----
        float iv = fsig(gi);
        float fv = fsig(gf);
        float gv = ftanh(gg);
        float ov = fsig(go);
        c = fv * c + iv * gv;
        float h = ov * ftanh(c);

        hop[(long long)t * HID] = h;     // fire-and-forget coalesced store
        h_s[j] = h;                      // next iter's reads wait via lgkmcnt
    }
}

// out(r) = h(r,:) . fc_w + fc_b   — trivial GEMV epilogue, off the critical path
__global__ __launch_bounds__(256) void fc_k(
    const float* __restrict__ h, const float* __restrict__ fc_w,
    const float* __restrict__ fc_b, float* __restrict__ out, long long R)
{
    __shared__ __align__(16) float w_s[HID];
    if (threadIdx.x < HID) w_s[threadIdx.x] = fc_w[threadIdx.x];
    __syncthreads();

    long long r = (long long)blockIdx.x * 256 + threadIdx.x;
    if (r >= R) return;

    const float4* hp = (const float4*)(h + r * HID);
    const float4* wp = (const float4*)w_s;
    float s0 = 0.f, s1 = 0.f, s2 = 0.f, s3 = 0.f;
#pragma unroll
    for (int k = 0; k < 16; ++k) {
        float4 hvv = hp[k];
        float4 wvv = wp[k];      // wave-uniform LDS broadcast
        s0 += hvv.x * wvv.x;
        s1 += hvv.y * wvv.y;
        s2 += hvv.z * wvv.z;
        s3 += hvv.w * wvv.w;
    }
    out[r] = (s0 + s1) + (s2 + s3) + fc_b[0];
}

extern "C" void kernel_launch(void* const* d_in, const int* in_sizes, int n_in,
                              void* d_out, int out_size, void* d_ws, size_t ws_size,
                              hipStream_t stream)
{
    const float* x    = (const float*)d_in[0];
    const float* wih0 = (const float*)d_in[1];
    const float* whh0 = (const float*)d_in[2];
    const float* bih0 = (const float*)d_in[3];
    const float* bhh0 = (const float*)d_in[4];
    const float* wih1 = (const float*)d_in[5];
    const float* whh1 = (const float*)d_in[6];
    const float* bih1 = (const float*)d_in[7];
    const float* bhh1 = (const float*)d_in[8];
    const float* wih2 = (const float*)d_in[9];
    const float* whh2 = (const float*)d_in[10];
    const float* bih2 = (const float*)d_in[11];
    const float* bhh2 = (const float*)d_in[12];
    const float* fcw  = (const float*)d_in[13];
    const float* fcb  = (const float*)d_in[14];
    float* outp = (float*)d_out;

    const long long R = (long long)BB * TT;      // 524288 rows
    float* pre  = (float*)d_ws;                  // R*256 fp32 = 512 MB
    float* hbuf = pre + R * 256;                 // R*64  fp32 = 128 MB

    const int gemm_grid = (int)(R / 64);         // 8192

    // layer 0
    gemm_pre_k<<<gemm_grid, 256, 0, stream>>>(x, wih0, bih0, bhh0, pre, 128);
    lstm_rec_k<<<BB, 64, 0, stream>>>(pre, whh0, hbuf);
    // layer 1
    gemm_pre_k<<<gemm_grid, 256, 0, stream>>>(hbuf, wih1, bih1, bhh1, pre, 64);
    lstm_rec_k<<<BB, 64, 0, stream>>>(pre, whh1, hbuf);
    // layer 2
    gemm_pre_k<<<gemm_grid, 256, 0, stream>>>(hbuf, wih2, bih2, bhh2, pre, 64);
    lstm_rec_k<<<BB, 64, 0, stream>>>(pre, whh2, hbuf);
    // FC epilogue
    fc_k<<<(int)(R / 256), 256, 0, stream>>>(hbuf, fcw, fcb, outp, R);
}

// Round 4
// 5932.817 us; speedup vs baseline: 1.1255x; 1.1255x over previous
//
#include <hip/hip_runtime.h>

#define TT 2048
#define BB 256
#define HID 64

typedef float f32x4 __attribute__((ext_vector_type(4)));

__device__ __forceinline__ float frcp(float x) { return __builtin_amdgcn_rcpf(x); }
__device__ __forceinline__ float fsig(float x) { return frcp(1.f + __expf(-x)); }
// tanh(x) = 1 - 2/(1+e^{2x}) : stable at +/-inf (no inf-inf)
__device__ __forceinline__ float ftanh(float x) { return 1.f - 2.f * frcp(1.f + __expf(2.f * x)); }

// pre = in(R,K) @ W(256,K)^T + b_ih + b_hh  -> out(R,256)
// block: 256 threads, tile 64 rows x 256 cols, k-chunks of 16.  (unchanged, proven)
__global__ __launch_bounds__(256, 2) void gemm_pre_k(
    const float* __restrict__ in, const float* __restrict__ W,
    const float* __restrict__ b_ih, const float* __restrict__ b_hh,
    float* __restrict__ out, int K)
{
    __shared__ __align__(16) float in_s[64][20];   // +4 pad keeps float4 align, breaks conflicts
    __shared__ __align__(16) float w_s[16][256];   // transposed W chunk: w_s[k][g]

    const int tid = threadIdx.x;
    const int tx = tid & 15, ty = tid >> 4;
    const long long row0 = (long long)blockIdx.x * 64;

    float4 bias[4];
    {
        const float4* bi4 = (const float4*)b_ih;
        const float4* bh4 = (const float4*)b_hh;
#pragma unroll
        for (int jj = 0; jj < 4; ++jj) {
            float4 a = bi4[tx * 4 + jj], b = bh4[tx * 4 + jj];
            bias[jj] = make_float4(a.x + b.x, a.y + b.y, a.z + b.z, a.w + b.w);
        }
    }

    float4 acc[4][4];
#pragma unroll
    for (int i = 0; i < 4; ++i)
#pragma unroll
        for (int j = 0; j < 4; ++j) acc[i][j] = make_float4(0.f, 0.f, 0.f, 0.f);

    const int rs = tid >> 2;   // 0..63 staging row
    const int kq = tid & 3;    // 0..3 staging k-quarter

    for (int kc = 0; kc < K; kc += 16) {
        __syncthreads();
        float4 iv = *(const float4*)(in + (row0 + rs) * K + kc + kq * 4);
        *(float4*)(&in_s[rs][kq * 4]) = iv;
        const float* wr = W + (long long)tid * K + kc;
        float4 w0 = ((const float4*)wr)[0];
        float4 w1 = ((const float4*)wr)[1];
        float4 w2 = ((const float4*)wr)[2];
        float4 w3 = ((const float4*)wr)[3];
        w_s[0][tid] = w0.x;  w_s[1][tid] = w0.y;  w_s[2][tid] = w0.z;  w_s[3][tid] = w0.w;
        w_s[4][tid] = w1.x;  w_s[5][tid] = w1.y;  w_s[6][tid] = w1.z;  w_s[7][tid] = w1.w;
        w_s[8][tid] = w2.x;  w_s[9][tid] = w2.y;  w_s[10][tid] = w2.z; w_s[11][tid] = w2.w;
        w_s[12][tid] = w3.x; w_s[13][tid] = w3.y; w_s[14][tid] = w3.z; w_s[15][tid] = w3.w;
        __syncthreads();

#pragma unroll
        for (int k2 = 0; k2 < 4; ++k2) {
            float4 a[4];
#pragma unroll
            for (int i = 0; i < 4; ++i) a[i] = *(const float4*)(&in_s[ty * 4 + i][k2 * 4]);
#pragma unroll
            for (int kk = 0; kk < 4; ++kk) {
                const int k = k2 * 4 + kk;
                float4 wv[4];
#pragma unroll
                for (int jj = 0; jj < 4; ++jj) wv[jj] = *(const float4*)(&w_s[k][tx * 16 + jj * 4]);
#pragma unroll
                for (int i = 0; i < 4; ++i) {
                    const float av = ((const float*)&a[i])[kk];
#pragma unroll
                    for (int jj = 0; jj < 4; ++jj) {
                        acc[i][jj].x += av * wv[jj].x;
                        acc[i][jj].y += av * wv[jj].y;
                        acc[i][jj].z += av * wv[jj].z;
                        acc[i][jj].w += av * wv[jj].w;
                    }
                }
            }
        }
    }

#pragma unroll
    for (int i = 0; i < 4; ++i) {
        float4* op = (float4*)(out + (row0 + ty * 4 + i) * 256 + tx * 16);
#pragma unroll
        for (int jj = 0; jj < 4; ++jj) {
            float4 v = acc[i][jj];
            v.x += bias[jj].x; v.y += bias[jj].y; v.z += bias[jj].z; v.w += bias[jj].w;
            op[jj] = v;
        }
    }
}

// Recurrent kernel — ONE WAVE per batch element, gates lane-local.
//  - 64 threads/block, block b = batch element b. Lane j owns h-index j and
//    computes all four of its gates: W_hh rows j, j+64, j+128, j+192 = 256
//    floats = 256 VGPRs, FORCED resident via amdgpu_waves_per_eu(1,1)
//    (allocator may use the full 512-VGPR budget at 1 wave/SIMD).
//  - t-loop unrolled x4 with a STATIC 4-slot prefetch buffer: no register
//    rotation copies; each slot reloads itself for t+4 right after its use.
//    16 dwords in flight ~= 4 steps (~2000 cyc) of cover > HBM latency.
//  - NO barriers. Only LDS: 64-float h broadcast (wave-uniform ds_read_b128,
//    conflict-free), write->read ordered within the wave by lgkmcnt.
__global__ __launch_bounds__(64)
__attribute__((amdgpu_waves_per_eu(1, 1)))
void lstm_rec_k(
    const float* __restrict__ pre, const float* __restrict__ w_hh,
    float* __restrict__ h_out)
{
    __shared__ __align__(16) float h_s[HID];

    const int j = threadIdx.x;   // 0..63 = h index
    const int b = blockIdx.x;

    // W_hh rows for lane j's four gates: 4 x 64 floats = 256 VGPRs
    f32x4 wq[4][16];
#pragma unroll
    for (int q = 0; q < 4; ++q) {
        const f32x4* wr = (const f32x4*)(w_hh + (q * HID + j) * HID);
#pragma unroll
        for (int k = 0; k < 16; ++k) wq[q][k] = wr[k];
    }

    h_s[j] = 0.f;
    float c = 0.f;

    // 4-slot static prefetch of pre[b][t][q*64+j], q=0..3
    const float* pp = pre + (long long)b * TT * 256;
    float4 pb[4];
#pragma unroll
    for (int u = 0; u < 4; ++u) {
        pb[u].x = pp[u * 256 + j];
        pb[u].y = pp[u * 256 + 64 + j];
        pb[u].z = pp[u * 256 + 128 + j];
        pb[u].w = pp[u * 256 + 192 + j];
    }

    float* hop = h_out + (long long)b * TT * HID + j;

    for (int tb = 0; tb < TT; tb += 4) {
        const float* pn = pp + (long long)(tb + 4) * 256;  // reload base (t+4)
        const bool do_pf = (tb + 4 < TT);                  // block-uniform
#pragma unroll
        for (int u = 0; u < 4; ++u) {
            const int t = tb + u;

            // ---- 4 gate dots over the h broadcast (shared ds_read per k) ----
            f32x4 a0 = (f32x4)(0.f), a1 = (f32x4)(0.f);
            f32x4 a2 = (f32x4)(0.f), a3 = (f32x4)(0.f);
            const f32x4* h4 = (const f32x4*)h_s;
#pragma unroll
            for (int k = 0; k < 16; ++k) {
                f32x4 hv = h4[k];            // wave-uniform broadcast read
                a0 += wq[0][k] * hv;
                a1 += wq[1][k] * hv;
                a2 += wq[2][k] * hv;
                a3 += wq[3][k] * hv;
            }
            float gi = pb[u].x + ((a0.x + a0.y) + (a0.z + a0.w));
            float gf = pb[u].y + ((a1.x + a1.y) + (a1.z + a1.w));
            float gg = pb[u].z + ((a2.x + a2.y) + (a2.z + a2.w));
            float go = pb[u].w + ((a3.x + a3.y) + (a3.z + a3.w));

            // slot reload for t+4 (static index, no rotation copies)
            if (do_pf) {
                pb[u].x = pn[u * 256 + j];
                pb[u].y = pn[u * 256 + 64 + j];
                pb[u].z = pn[u * 256 + 128 + j];
                pb[u].w = pn[u * 256 + 192 + j];
            }

            // ---- activations + state update (all lane-local) ----
            float iv = fsig(gi);
            float fv = fsig(gf);
            float gv = ftanh(gg);
            float ov = fsig(go);
            c = fv * c + iv * gv;
            float h = ov * ftanh(c);

            hop[(long long)t * HID] = h;     // fire-and-forget coalesced store
            h_s[j] = h;                      // next iter's reads wait via lgkmcnt
        }
    }
}

// out(r) = h(r,:) . fc_w + fc_b   — trivial GEMV epilogue, off the critical path
__global__ __launch_bounds__(256) void fc_k(
    const float* __restrict__ h, const float* __restrict__ fc_w,
    const float* __restrict__ fc_b, float* __restrict__ out, long long R)
{
    __shared__ __align__(16) float w_s[HID];
    if (threadIdx.x < HID) w_s[threadIdx.x] = fc_w[threadIdx.x];
    __syncthreads();

    long long r = (long long)blockIdx.x * 256 + threadIdx.x;
    if (r >= R) return;

    const float4* hp = (const float4*)(h + r * HID);
    const float4* wp = (const float4*)w_s;
    float s0 = 0.f, s1 = 0.f, s2 = 0.f, s3 = 0.f;
#pragma unroll
    for (int k = 0; k < 16; ++k) {
        float4 hvv = hp[k];
        float4 wvv = wp[k];      // wave-uniform LDS broadcast
        s0 += hvv.x * wvv.x;
        s1 += hvv.y * wvv.y;
        s2 += hvv.z * wvv.z;
        s3 += hvv.w * wvv.w;
    }
    out[r] = (s0 + s1) + (s2 + s3) + fc_b[0];
}

extern "C" void kernel_launch(void* const* d_in, const int* in_sizes, int n_in,
                              void* d_out, int out_size, void* d_ws, size_t ws_size,
                              hipStream_t stream)
{
    const float* x    = (const float*)d_in[0];
    const float* wih0 = (const float*)d_in[1];
    const float* whh0 = (const float*)d_in[2];
    const float* bih0 = (const float*)d_in[3];
    const float* bhh0 = (const float*)d_in[4];
    const float* wih1 = (const float*)d_in[5];
    const float* whh1 = (const float*)d_in[6];
    const float* bih1 = (const float*)d_in[7];
    const float* bhh1 = (const float*)d_in[8];
    const float* wih2 = (const float*)d_in[9];
    const float* whh2 = (const float*)d_in[10];
    const float* bih2 = (const float*)d_in[11];
    const float* bhh2 = (const float*)d_in[12];
    const float* fcw  = (const float*)d_in[13];
    const float* fcb  = (const float*)d_in[14];
    float* outp = (float*)d_out;

    const long long R = (long long)BB * TT;      // 524288 rows
    float* pre  = (float*)d_ws;                  // R*256 fp32 = 512 MB
    float* hbuf = pre + R * 256;                 // R*64  fp32 = 128 MB

    const int gemm_grid = (int)(R / 64);         // 8192

    // layer 0
    gemm_pre_k<<<gemm_grid, 256, 0, stream>>>(x, wih0, bih0, bhh0, pre, 128);
    lstm_rec_k<<<BB, 64, 0, stream>>>(pre, whh0, hbuf);
    // layer 1
    gemm_pre_k<<<gemm_grid, 256, 0, stream>>>(hbuf, wih1, bih1, bhh1, pre, 64);
    lstm_rec_k<<<BB, 64, 0, stream>>>(pre, whh1, hbuf);
    // layer 2
    gemm_pre_k<<<gemm_grid, 256, 0, stream>>>(hbuf, wih2, bih2, bhh2, pre, 64);
    lstm_rec_k<<<BB, 64, 0, stream>>>(pre, whh2, hbuf);
    // FC epilogue
    fc_k<<<(int)(R / 256), 256, 0, stream>>>(hbuf, fcw, fcb, outp, R);
}

// Round 5
// 4371.106 us; speedup vs baseline: 1.5276x; 1.3573x over previous
//
#include <hip/hip_runtime.h>

#define TT 2048
#define BB 256
#define HID 64

typedef float f32x4 __attribute__((ext_vector_type(4)));

__device__ __forceinline__ float frcp(float x) { return __builtin_amdgcn_rcpf(x); }
__device__ __forceinline__ float fsig(float x) { return frcp(1.f + __expf(-x)); }
// tanh(x) = 1 - 2/(1+e^{2x}) : stable at +/-inf (no inf-inf)
__device__ __forceinline__ float ftanh(float x) { return 1.f - 2.f * frcp(1.f + __expf(2.f * x)); }

// Raw workgroup barrier: waits LDS ops only (lgkmcnt), does NOT drain vmcnt —
// global prefetch loads / h-stores stay in flight across the barrier.
__device__ __forceinline__ void wg_barrier_lds() {
    asm volatile("s_waitcnt lgkmcnt(0)" ::: "memory");
    __builtin_amdgcn_s_barrier();
    asm volatile("" ::: "memory");
}

// Pin 4 f32x4 values into arch VGPRs: the (empty) asm "modifies" them, so the
// compiler cannot rematerialize from memory or park them in AGPRs.
#define PIN4(a, b, c, d) asm volatile("" : "+v"(a), "+v"(b), "+v"(c), "+v"(d))

// pre = in(R,K) @ W(256,K)^T + b_ih + b_hh  -> out(R,256)
// block: 256 threads, tile 64 rows x 256 cols, k-chunks of 16.  (unchanged, proven)
__global__ __launch_bounds__(256, 2) void gemm_pre_k(
    const float* __restrict__ in, const float* __restrict__ W,
    const float* __restrict__ b_ih, const float* __restrict__ b_hh,
    float* __restrict__ out, int K)
{
    __shared__ __align__(16) float in_s[64][20];   // +4 pad keeps float4 align, breaks conflicts
    __shared__ __align__(16) float w_s[16][256];   // transposed W chunk: w_s[k][g]

    const int tid = threadIdx.x;
    const int tx = tid & 15, ty = tid >> 4;
    const long long row0 = (long long)blockIdx.x * 64;

    float4 bias[4];
    {
        const float4* bi4 = (const float4*)b_ih;
        const float4* bh4 = (const float4*)b_hh;
#pragma unroll
        for (int jj = 0; jj < 4; ++jj) {
            float4 a = bi4[tx * 4 + jj], b = bh4[tx * 4 + jj];
            bias[jj] = make_float4(a.x + b.x, a.y + b.y, a.z + b.z, a.w + b.w);
        }
    }

    float4 acc[4][4];
#pragma unroll
    for (int i = 0; i < 4; ++i)
#pragma unroll
        for (int j = 0; j < 4; ++j) acc[i][j] = make_float4(0.f, 0.f, 0.f, 0.f);

    const int rs = tid >> 2;   // 0..63 staging row
    const int kq = tid & 3;    // 0..3 staging k-quarter

    for (int kc = 0; kc < K; kc += 16) {
        __syncthreads();
        float4 iv = *(const float4*)(in + (row0 + rs) * K + kc + kq * 4);
        *(float4*)(&in_s[rs][kq * 4]) = iv;
        const float* wr = W + (long long)tid * K + kc;
        float4 w0 = ((const float4*)wr)[0];
        float4 w1 = ((const float4*)wr)[1];
        float4 w2 = ((const float4*)wr)[2];
        float4 w3 = ((const float4*)wr)[3];
        w_s[0][tid] = w0.x;  w_s[1][tid] = w0.y;  w_s[2][tid] = w0.z;  w_s[3][tid] = w0.w;
        w_s[4][tid] = w1.x;  w_s[5][tid] = w1.y;  w_s[6][tid] = w1.z;  w_s[7][tid] = w1.w;
        w_s[8][tid] = w2.x;  w_s[9][tid] = w2.y;  w_s[10][tid] = w2.z; w_s[11][tid] = w2.w;
        w_s[12][tid] = w3.x; w_s[13][tid] = w3.y; w_s[14][tid] = w3.z; w_s[15][tid] = w3.w;
        __syncthreads();

#pragma unroll
        for (int k2 = 0; k2 < 4; ++k2) {
            float4 a[4];
#pragma unroll
            for (int i = 0; i < 4; ++i) a[i] = *(const float4*)(&in_s[ty * 4 + i][k2 * 4]);
#pragma unroll
            for (int kk = 0; kk < 4; ++kk) {
                const int k = k2 * 4 + kk;
                float4 wv[4];
#pragma unroll
                for (int jj = 0; jj < 4; ++jj) wv[jj] = *(const float4*)(&w_s[k][tx * 16 + jj * 4]);
#pragma unroll
                for (int i = 0; i < 4; ++i) {
                    const float av = ((const float*)&a[i])[kk];
#pragma unroll
                    for (int jj = 0; jj < 4; ++jj) {
                        acc[i][jj].x += av * wv[jj].x;
                        acc[i][jj].y += av * wv[jj].y;
                        acc[i][jj].z += av * wv[jj].z;
                        acc[i][jj].w += av * wv[jj].w;
                    }
                }
            }
        }
    }

#pragma unroll
    for (int i = 0; i < 4; ++i) {
        float4* op = (float4*)(out + (row0 + ty * 4 + i) * 256 + tx * 16);
#pragma unroll
        for (int jj = 0; jj < 4; ++jj) {
            float4 v = acc[i][jj];
            v.x += bias[jj].x; v.y += bias[jj].y; v.z += bias[jj].z; v.w += bias[jj].w;
            op[jj] = v;
        }
    }
}

// Recurrent kernel — TWO waves per batch element, 2 gates per lane per wave.
//  - block b = batch element b; 128 threads. Wave 0: gates i,f. Wave 1: g,o.
//    Lane j owns h-index j: weight rows (2w)*64+j and (2w+1)*64+j = 128 VGPRs,
//    inside the 256 arch-VGPR cap (R4 showed 256 weights/lane CANNOT be arch-
//    resident -> AGPR shuttle ~600 cyc/step). Weights pinned via empty asm.
//  - per-step: both waves dot over the full h broadcast (private h_w[w] copy,
//    wave-uniform ds_read_b128, conflict-free), activate own 2 gates, exchange
//    activated gates via double-buffered LDS (conflict-free: lane j <-> dword j)
//    with ONE lgkm-only barrier; both waves redundantly update (c,h).
//  - pre[] prefetched 4 steps deep (static slots, no rotation); h store
//    fire-and-forget (wave 0 only); nothing drains vmcnt at the barrier.
__global__ __launch_bounds__(128)
__attribute__((amdgpu_waves_per_eu(1, 1)))
void lstm_rec_k(
    const float* __restrict__ pre, const float* __restrict__ w_hh,
    float* __restrict__ h_out)
{
    __shared__ __align__(16) float h_w[2][HID];   // per-wave private h copy
    __shared__ float gx[2][2][2][HID];            // [t&1][wave][gate-in-wave][j]

    const int tid = threadIdx.x;
    const int w = tid >> 6;      // wave id 0..1
    const int j = tid & 63;      // lane id = h index
    const int b = blockIdx.x;

    // weight rows for this wave's two gates (gate qA=2w, qB=2w+1), h-index j
    f32x4 wA[16], wB[16];
    {
        const f32x4* ra = (const f32x4*)(w_hh + ((2 * w + 0) * HID + j) * HID);
        const f32x4* rb = (const f32x4*)(w_hh + ((2 * w + 1) * HID + j) * HID);
#pragma unroll
        for (int k = 0; k < 16; ++k) { wA[k] = ra[k]; wB[k] = rb[k]; }
    }

    h_w[w][j] = 0.f;
    float c = 0.f;

    // 4-slot static prefetch: lane j of wave w needs pre[t][w*128 + j] (gate A)
    // and pre[t][w*128 + 64 + j] (gate B)
    const float* pp = pre + (long long)b * TT * 256 + w * 128 + j;
    float2 pb[4];
#pragma unroll
    for (int u = 0; u < 4; ++u) {
        pb[u].x = pp[u * 256];
        pb[u].y = pp[u * 256 + 64];
    }

    float* hop = h_out + (long long)b * TT * HID + j;
    const bool is_w0 = (w == 0);

    for (int tb = 0; tb < TT; tb += 4) {
        // keep the 128 weight VGPRs arch-resident: asm "modifies" them, so no
        // rematerialization-from-memory and no AGPR parking is possible.
#pragma unroll
        for (int k = 0; k < 16; k += 4) PIN4(wA[k], wA[k + 1], wA[k + 2], wA[k + 3]);
#pragma unroll
        for (int k = 0; k < 16; k += 4) PIN4(wB[k], wB[k + 1], wB[k + 2], wB[k + 3]);

        const float* pn = pp + (long long)(tb + 4) * 256;  // reload base (t+4)
        const bool do_pf = (tb + 4 < TT);                  // block-uniform
#pragma unroll
        for (int u = 0; u < 4; ++u) {
            const int t = tb + u;
            const int buf = t & 1;

            // ---- two gate dots over the h broadcast ----
            f32x4 a0 = (f32x4)(0.f), a1 = (f32x4)(0.f);
            const f32x4* h4 = (const f32x4*)(&h_w[w][0]);
#pragma unroll
            for (int k = 0; k < 16; ++k) {
                f32x4 hv = h4[k];            // wave-uniform broadcast read
                a0 += wA[k] * hv;
                a1 += wB[k] * hv;
            }
            float gA = pb[u].x + ((a0.x + a0.y) + (a0.z + a0.w));
            float gB = pb[u].y + ((a1.x + a1.y) + (a1.z + a1.w));

            // slot reload for t+4 (static index, no rotation copies)
            if (do_pf) {
                pb[u].x = pn[u * 256];
                pb[u].y = pn[u * 256 + 64];
            }

            // own activations: wave0 = sig(i),sig(f); wave1 = tanh(g),sig(o)
            float actA = is_w0 ? fsig(gA) : ftanh(gA);
            float actB = fsig(gB);

            gx[buf][w][0][j] = actA;         // conflict-free (lane j -> dword j)
            gx[buf][w][1][j] = actB;

            wg_barrier_lds();                // lgkm-only; vmcnt stays in flight

            // foreign activated gates
            float fA = gx[buf][w ^ 1][0][j];
            float fB = gx[buf][w ^ 1][1][j];

            float iv = is_w0 ? actA : fA;
            float fv = is_w0 ? actB : fB;
            float gv = is_w0 ? fA : actA;
            float ov = is_w0 ? fB : actB;

            c = fv * c + iv * gv;
            float h = ov * ftanh(c);

            if (is_w0) hop[(long long)t * HID] = h;   // fire-and-forget store
            h_w[w][j] = h;                   // own-wave copy; next dot waits lgkm
        }
    }
}

// out(r) = h(r,:) . fc_w + fc_b   — trivial GEMV epilogue, off the critical path
__global__ __launch_bounds__(256) void fc_k(
    const float* __restrict__ h, const float* __restrict__ fc_w,
    const float* __restrict__ fc_b, float* __restrict__ out, long long R)
{
    __shared__ __align__(16) float w_s[HID];
    if (threadIdx.x < HID) w_s[threadIdx.x] = fc_w[threadIdx.x];
    __syncthreads();

    long long r = (long long)blockIdx.x * 256 + threadIdx.x;
    if (r >= R) return;

    const float4* hp = (const float4*)(h + r * HID);
    const float4* wp = (const float4*)w_s;
    float s0 = 0.f, s1 = 0.f, s2 = 0.f, s3 = 0.f;
#pragma unroll
    for (int k = 0; k < 16; ++k) {
        float4 hvv = hp[k];
        float4 wvv = wp[k];      // wave-uniform LDS broadcast
        s0 += hvv.x * wvv.x;
        s1 += hvv.y * wvv.y;
        s2 += hvv.z * wvv.z;
        s3 += hvv.w * wvv.w;
    }
    out[r] = (s0 + s1) + (s2 + s3) + fc_b[0];
}

extern "C" void kernel_launch(void* const* d_in, const int* in_sizes, int n_in,
                              void* d_out, int out_size, void* d_ws, size_t ws_size,
                              hipStream_t stream)
{
    const float* x    = (const float*)d_in[0];
    const float* wih0 = (const float*)d_in[1];
    const float* whh0 = (const float*)d_in[2];
    const float* bih0 = (const float*)d_in[3];
    const float* bhh0 = (const float*)d_in[4];
    const float* wih1 = (const float*)d_in[5];
    const float* whh1 = (const float*)d_in[6];
    const float* bih1 = (const float*)d_in[7];
    const float* bhh1 = (const float*)d_in[8];
    const float* wih2 = (const float*)d_in[9];
    const float* whh2 = (const float*)d_in[10];
    const float* bih2 = (const float*)d_in[11];
    const float* bhh2 = (const float*)d_in[12];
    const float* fcw  = (const float*)d_in[13];
    const float* fcb  = (const float*)d_in[14];
    float* outp = (float*)d_out;

    const long long R = (long long)BB * TT;      // 524288 rows
    float* pre  = (float*)d_ws;                  // R*256 fp32 = 512 MB
    float* hbuf = pre + R * 256;                 // R*64  fp32 = 128 MB

    const int gemm_grid = (int)(R / 64);         // 8192

    // layer 0
    gemm_pre_k<<<gemm_grid, 256, 0, stream>>>(x, wih0, bih0, bhh0, pre, 128);
    lstm_rec_k<<<BB, 128, 0, stream>>>(pre, whh0, hbuf);
    // layer 1
    gemm_pre_k<<<gemm_grid, 256, 0, stream>>>(hbuf, wih1, bih1, bhh1, pre, 64);
    lstm_rec_k<<<BB, 128, 0, stream>>>(pre, whh1, hbuf);
    // layer 2
    gemm_pre_k<<<gemm_grid, 256, 0, stream>>>(hbuf, wih2, bih2, bhh2, pre, 64);
    lstm_rec_k<<<BB, 128, 0, stream>>>(pre, whh2, hbuf);
    // FC epilogue
    fc_k<<<(int)(R / 256), 256, 0, stream>>>(hbuf, fcw, fcb, outp, R);
}